// Round 9
// baseline (63.182 us; speedup 1.0000x reference)
//
#include <hip/hip_runtime.h>

// B=32, T=4096, D=512. out[b] = retrieved[b] @ W.T + bias where retrieved[b]
// is the LAST write row (order n = t*B + b) whose int32 hash equals query b's
// hash. Hash = (int)trunc of numpy-pairwise f32 sum of row*1000 — bit-exact
// reproduction verified R1-R8.
//
// R9 = R8 with nontemporal hints REMOVED (single-variable A/B). Rationale:
// x is exactly 256 MiB and the harness replays without cache flushes — the
// working set (x[:, :T-1] + W ~ 257 MB) fits the 256 MiB Infinity Cache, so
// letting x allocate in L3 can lift the stream above the HBM ceiling.
// R6 evidence: FETCH_SIZE=135MB (half of x already L3-served even with nt).

constexpr int Dm = 512;
constexpr int LROW = 544; // padded: elem idx stored at idx + 8*(idx>>7)

typedef float nt_f4 __attribute__((ext_vector_type(4)));

// Exact numpy pairwise sum of 512 f32 (each *1000 in f32 first), by a 32-lane
// group. lane=(k<<3)|j; k=128-block, j=accumulator. Per block: r[j] sequential
// 16 terms; combine ((r0+r1)+(r2+r3))+((r4+r5)+(r6+r7)); blocks (p0+p1)+(p2+p3).
// Butterfly == numpy tree (f32 add commutative). Bit-exact (R1 verified).
__device__ __forceinline__ int hash_row_lds(const float* rowp, int lane) {
#pragma clang fp contract(off)
    int k = lane >> 3, j = lane & 7;
    const float* p = rowp + k * 136 + j;
    float r = p[0] * 1000.0f;
#pragma unroll
    for (int i = 1; i < 16; ++i) {
        float prod = p[8 * i] * 1000.0f;
        r = r + prod;
    }
    r = r + __shfl_xor(r, 1);
    r = r + __shfl_xor(r, 2);
    r = r + __shfl_xor(r, 4);
    r = r + __shfl_xor(r, 8);
    r = r + __shfl_xor(r, 16);
    return (int)r; // trunc toward zero
}

// One query row per block (single wave). Block 0 also inits best[].
__global__ __launch_bounds__(64) void init_kernel(const float* __restrict__ x,
                                                  int* __restrict__ qh_i,
                                                  float* __restrict__ qh_f,
                                                  int* __restrict__ best,
                                                  int Bv, int Tv) {
    __shared__ float slab[LROW];
    const int lane = threadIdx.x;
    const int bq = blockIdx.x;
    if (bq == 0 && lane < Bv) best[lane] = -1;
    if (bq >= Bv) return;
    const float* row = x + ((long)bq * Tv + (Tv - 1)) * Dm;
    const int idx = lane * 8;
    const int off = idx + 8 * (idx >> 7);
    *reinterpret_cast<float4*>(&slab[off]) = *reinterpret_cast<const float4*>(row + idx);
    *reinterpret_cast<float4*>(&slab[off + 4]) = *reinterpret_cast<const float4*>(row + idx + 4);
    __syncthreads();
    if (lane < 32) {
        int h = hash_row_lds(slab, lane);
        if (lane == 0) { qh_i[bq] = h; qh_f[bq] = (float)h; }
    }
}

// Batched stream: each wave owns bpw batches of 8 consecutive memory-order
// rows. Lane L owns row (L>>3), cols (L&7)*4 + c*32 (16 dwordx4 loads).
// Screen: per-lane sum of 64 floats + 3-step shfl in 8-lane groups; sound
// bound ~2.0, eps=8.0 (4x margin, ~0.9% flagged). Flagged rows re-read
// (cache-warm) into the verified 64-lane LDS exact numpy-order hash path.
__global__ __launch_bounds__(256) void stream_kernel(const float* __restrict__ x,
                                                     const int* __restrict__ qh_i,
                                                     const float* __restrict__ qh_f,
                                                     int* __restrict__ best,
                                                     int Bv, int Tv, int bpw) {
    __shared__ float slab[4][LROW];
    const int tid = threadIdx.x;
    const int wslab = tid >> 6;
    const int lane = tid & 63;
    const int g8 = lane & 7;    // column slot within 8-lane group
    const int rloc = lane >> 3; // row within batch
    const int Tm1 = Tv - 1;
    const long NR = (long)Bv * Tm1;
    const long NBat = (NR + 7) >> 3;

    int qi = (int)0x80000000;
    if (lane < Bv) qi = qh_i[lane];
    float qfv[4];
#pragma unroll
    for (int k = 0; k < 4; ++k) {
        int q = g8 * 4 + k;
        qfv[k] = (q < Bv) ? qh_f[q] : __builtin_inff();
    }

    // LDS offsets for the exact path (padded layout, see hash_row_lds)
    const int pad0 = lane * 4 + 8 * (lane >> 5);       // elems [0,256)
    const int pad1 = 272 + lane * 4 + 8 * (lane >> 5); // elems [256,512)

    const int wave_id = blockIdx.x * 4 + wslab;
    long bat = (long)wave_id * bpw;
    const long bend = min(bat + bpw, NBat);
    if (bat >= bend) return;

    long g0 = bat * 8;
    int b0 = (int)(g0 / Tm1); // one division per wave
    int t0 = (int)(g0 - (long)b0 * Tm1);

    while (bat < bend) {
        // this lane's row within the batch (batches can cross one b-boundary)
        const bool rv = (g0 + rloc) < NR;
        int tl = t0 + rloc, bl = b0;
        if (tl >= Tm1) { tl -= Tm1; bl += 1; }
        if (!rv) { tl = 0; bl = 0; } // safe dummy address
        const float* base = x + ((long)bl * Tv + tl) * Dm + g8 * 4;

        nt_f4 v[16];
#pragma unroll
        for (int c = 0; c < 16; ++c)
            v[c] = *reinterpret_cast<const nt_f4*>(base + c * 32); // cacheable

        // per-lane sum of its 64 floats (4 independent accumulators)
        float a0 = 0.f, a1 = 0.f, a2 = 0.f, a3 = 0.f;
#pragma unroll
        for (int c = 0; c < 16; c += 4) {
            a0 += (v[c].x + v[c].y) + (v[c].z + v[c].w);
            a1 += (v[c + 1].x + v[c + 1].y) + (v[c + 1].z + v[c + 1].w);
            a2 += (v[c + 2].x + v[c + 2].y) + (v[c + 2].z + v[c + 2].w);
            a3 += (v[c + 3].x + v[c + 3].y) + (v[c + 3].z + v[c + 3].w);
        }
        float s = (a0 + a1) + (a2 + a3);
        s += __shfl_xor(s, 1); // 3-step reduce within the 8-lane group
        s += __shfl_xor(s, 2);
        s += __shfl_xor(s, 4);
        s *= 1000.0f;

        bool cand = rv && (fabsf(s - qfv[0]) <= 8.0f || fabsf(s - qfv[1]) <= 8.0f ||
                           fabsf(s - qfv[2]) <= 8.0f || fabsf(s - qfv[3]) <= 8.0f);
        const unsigned long long m = __ballot(cand);

        if (m) { // rare: exact numpy-order hash for each flagged row
            unsigned rmask = 0;
#pragma unroll
            for (int r = 0; r < 8; ++r)
                if ((m >> (8 * r)) & 0xFFull) rmask |= 1u << r;
            while (rmask) {
                const int r = __builtin_ctz(rmask);
                rmask &= rmask - 1;
                int tr = t0 + r, br = b0;
                if (tr >= Tm1) { tr -= Tm1; br += 1; }
                // whole wave re-reads the 2KB row (cache-warm), stages padded
                const float* row = x + ((long)br * Tv + tr) * Dm + lane * 4;
                float4 w0 = *reinterpret_cast<const float4*>(row);
                float4 w1 = *reinterpret_cast<const float4*>(row + 256);
                asm volatile("s_waitcnt lgkmcnt(0)" ::: "memory");
                *reinterpret_cast<float4*>(&slab[wslab][pad0]) = w0;
                *reinterpret_cast<float4*>(&slab[wslab][pad1]) = w1;
                asm volatile("s_waitcnt lgkmcnt(0)" ::: "memory");
                int h = hash_row_lds(slab[wslab], lane & 31);
                if (lane < Bv && h == qi) atomicMax(&best[lane], tr * Bv + br);
            }
        }

        // advance to next batch of 8 rows
        t0 += 8;
        if (t0 >= Tm1) { t0 -= Tm1; b0 += 1; }
        g0 += 8;
        ++bat;
    }
}

// out[b][d] = dot(W[d,:], retrieved) + bias[d]; 256 blocks = (b, 8 d-chunks).
__global__ __launch_bounds__(256) void out_kernel(const float* __restrict__ x,
                                                  const float* __restrict__ W,
                                                  const float* __restrict__ bias,
                                                  const int* __restrict__ best,
                                                  float* __restrict__ out,
                                                  int Bv, int Tv) {
    const int b = blockIdx.x >> 3;
    const int c = blockIdx.x & 7;
    const int w = threadIdx.x >> 6, lane = threadIdx.x & 63;
    const int idx = best[b];
    float r0, r1, r2, r3, r4, r5, r6, r7;
    if (idx >= 0) {
        int t = idx / Bv, bw = idx - (idx / Bv) * Bv; // n = t*B + b
        const float* row = x + ((long)bw * Tv + t) * Dm + lane * 8;
        float4 x0 = *reinterpret_cast<const float4*>(row);
        float4 x1 = *reinterpret_cast<const float4*>(row + 4);
        r0 = x0.x; r1 = x0.y; r2 = x0.z; r3 = x0.w;
        r4 = x1.x; r5 = x1.y; r6 = x1.z; r7 = x1.w;
    } else {
        r0 = r1 = r2 = r3 = r4 = r5 = r6 = r7 = 0.f;
    }
    for (int di = w; di < 64; di += 4) {
        int d = c * 64 + di;
        const float* wrow = W + (long)d * Dm + lane * 8;
        float4 w0 = *reinterpret_cast<const float4*>(wrow);
        float4 w1 = *reinterpret_cast<const float4*>(wrow + 4);
        float acc = w0.x * r0 + w0.y * r1 + w0.z * r2 + w0.w * r3 +
                    w1.x * r4 + w1.y * r5 + w1.z * r6 + w1.w * r7;
        acc += __shfl_xor(acc, 1);
        acc += __shfl_xor(acc, 2);
        acc += __shfl_xor(acc, 4);
        acc += __shfl_xor(acc, 8);
        acc += __shfl_xor(acc, 16);
        acc += __shfl_xor(acc, 32);
        if (lane == 0) out[(long)b * Dm + d] = acc + bias[d];
    }
}

extern "C" void kernel_launch(void* const* d_in, const int* in_sizes, int n_in,
                              void* d_out, int out_size, void* d_ws, size_t ws_size,
                              hipStream_t stream) {
    const float* x = (const float*)d_in[0];
    // d_in[1] = hx_list (unused by the reference)
    const float* W = (const float*)d_in[2];
    const float* bias = (const float*)d_in[3];
    float* out = (float*)d_out;

    int Bv = in_sizes[1];                 // 32
    long xs = (long)in_sizes[0];          // B*T*D
    int Tv = (int)(xs / ((long)Bv * Dm)); // 4096

    int* best = (int*)d_ws;               // [64]
    int* qh_i = (int*)d_ws + 64;          // [64]
    float* qh_f = (float*)d_ws + 128;     // [64]

    init_kernel<<<Bv, 64, 0, stream>>>(x, qh_i, qh_f, best, Bv, Tv);

    const int nblk = 2048;
    const long NR = (long)Bv * (Tv - 1);
    const long NBat = (NR + 7) >> 3;
    const int nwaves = nblk * 4;
    const int bpw = (int)((NBat + nwaves - 1) / nwaves);
    stream_kernel<<<nblk, 256, 0, stream>>>(x, qh_i, qh_f, best, Bv, Tv, bpw);

    out_kernel<<<Bv * 8, 256, 0, stream>>>(x, W, bias, best, out, Bv, Tv);
}

// Round 10
// 62.177 us; speedup vs baseline: 1.0162x; 1.0162x over previous
//
#include <hip/hip_runtime.h>

// B=32, T=4096, D=512. out[b] = retrieved[b] @ W.T + bias where retrieved[b]
// is the LAST write row (order n = t*B + b) whose int32 hash equals query b's
// hash. Hash = (int)trunc of numpy-pairwise f32 sum of row*1000 — bit-exact
// reproduction verified R1-R9.
//
// R10 = R8 (nt loads RESTORED — R9's A/B showed removing them costs +5.5us)
// with the init dispatch folded away: each stream block hashes the 32 query
// rows in a prologue (64KB, L2/L3-hot, overlaps the 2048-block launch ramp),
// and best[] reset is a 128B hipMemsetAsync. 2 real kernels + 1 tiny fill.

constexpr int Dm = 512;
constexpr int LROW = 544; // padded: elem idx stored at idx + 8*(idx>>7)

typedef float nt_f4 __attribute__((ext_vector_type(4))); // builtin-compatible

// Exact numpy pairwise sum of 512 f32 (each *1000 in f32 first), by a 32-lane
// group. lane=(k<<3)|j; k=128-block, j=accumulator. Per block: r[j] sequential
// 16 terms; combine ((r0+r1)+(r2+r3))+((r4+r5)+(r6+r7)); blocks (p0+p1)+(p2+p3).
// Butterfly == numpy tree (f32 add commutative). Bit-exact (R1 verified).
__device__ __forceinline__ int hash_row_lds(const float* rowp, int lane) {
#pragma clang fp contract(off)
    int k = lane >> 3, j = lane & 7;
    const float* p = rowp + k * 136 + j;
    float r = p[0] * 1000.0f;
#pragma unroll
    for (int i = 1; i < 16; ++i) {
        float prod = p[8 * i] * 1000.0f;
        r = r + prod;
    }
    r = r + __shfl_xor(r, 1);
    r = r + __shfl_xor(r, 2);
    r = r + __shfl_xor(r, 4);
    r = r + __shfl_xor(r, 8);
    r = r + __shfl_xor(r, 16);
    return (int)r; // trunc toward zero
}

// Batched stream with query-hash prologue. Each wave owns bpw batches of 8
// consecutive memory-order rows. Lane L owns row (L>>3), cols (L&7)*4 + c*32
// (16 nt dwordx4 loads, 16KB in flight/wave). Screen: per-lane sum of 64
// floats + 3-step shfl in 8-lane groups; sound bound ~2.0, eps=8.0 (4x
// margin, ~0.9% flagged). Flagged rows re-read (cache-warm) into the
// verified 64-lane LDS exact numpy-order hash path.
__global__ __launch_bounds__(256) void stream_kernel(const float* __restrict__ x,
                                                     int* __restrict__ best,
                                                     int Bv, int Tv, int bpw) {
    __shared__ float slab[4][LROW];
    __shared__ int qsh_i[32];
    __shared__ float qsh_f[32];
    const int tid = threadIdx.x;
    const int wslab = tid >> 6;
    const int lane = tid & 63;
    const int g8 = lane & 7;    // column slot within 8-lane group
    const int rloc = lane >> 3; // row within batch
    const int Tm1 = Tv - 1;
    const long NR = (long)Bv * Tm1;
    const long NBat = (NR + 7) >> 3;

    // LDS offsets for padded staging (see hash_row_lds layout)
    const int pad0 = lane * 4 + 8 * (lane >> 5);       // elems [0,256)
    const int pad1 = 272 + lane * 4 + 8 * (lane >> 5); // elems [256,512)

    // ---- prologue: this wave hashes queries 8w..8w+7 (L2/L3-hot rows) ----
    for (int i = 0; i < 8; ++i) {
        const int q = wslab * 8 + i;
        if (q < Bv) { // uniform per wave
            const float* qrow = x + ((long)q * Tv + (Tv - 1)) * Dm + lane * 4;
            float4 q0 = *reinterpret_cast<const float4*>(qrow);
            float4 q1 = *reinterpret_cast<const float4*>(qrow + 256);
            asm volatile("s_waitcnt lgkmcnt(0)" ::: "memory");
            *reinterpret_cast<float4*>(&slab[wslab][pad0]) = q0;
            *reinterpret_cast<float4*>(&slab[wslab][pad1]) = q1;
            asm volatile("s_waitcnt lgkmcnt(0)" ::: "memory");
            int h = hash_row_lds(slab[wslab], lane & 31);
            if (lane == 0) { qsh_i[q] = h; qsh_f[q] = (float)h; }
        }
    }
    __syncthreads(); // all 32 query hashes visible block-wide

    int qi = (int)0x80000000;
    if (lane < Bv) qi = qsh_i[lane];
    float qfv[4];
#pragma unroll
    for (int k = 0; k < 4; ++k) {
        int q = g8 * 4 + k;
        qfv[k] = (q < Bv) ? qsh_f[q] : __builtin_inff();
    }

    const int wave_id = blockIdx.x * 4 + wslab;
    long bat = (long)wave_id * bpw;
    const long bend = min(bat + bpw, NBat);
    if (bat >= bend) return;

    long g0 = bat * 8;
    int b0 = (int)(g0 / Tm1); // one division per wave
    int t0 = (int)(g0 - (long)b0 * Tm1);

    while (bat < bend) {
        // this lane's row within the batch (batches can cross one b-boundary)
        const bool rv = (g0 + rloc) < NR;
        int tl = t0 + rloc, bl = b0;
        if (tl >= Tm1) { tl -= Tm1; bl += 1; }
        if (!rv) { tl = 0; bl = 0; } // safe dummy address
        const float* base = x + ((long)bl * Tv + tl) * Dm + g8 * 4;

        nt_f4 v[16];
#pragma unroll
        for (int c = 0; c < 16; ++c)
            v[c] = __builtin_nontemporal_load(reinterpret_cast<const nt_f4*>(base + c * 32));

        // per-lane sum of its 64 floats (4 independent accumulators)
        float a0 = 0.f, a1 = 0.f, a2 = 0.f, a3 = 0.f;
#pragma unroll
        for (int c = 0; c < 16; c += 4) {
            a0 += (v[c].x + v[c].y) + (v[c].z + v[c].w);
            a1 += (v[c + 1].x + v[c + 1].y) + (v[c + 1].z + v[c + 1].w);
            a2 += (v[c + 2].x + v[c + 2].y) + (v[c + 2].z + v[c + 2].w);
            a3 += (v[c + 3].x + v[c + 3].y) + (v[c + 3].z + v[c + 3].w);
        }
        float s = (a0 + a1) + (a2 + a3);
        s += __shfl_xor(s, 1); // 3-step reduce within the 8-lane group
        s += __shfl_xor(s, 2);
        s += __shfl_xor(s, 4);
        s *= 1000.0f;

        bool cand = rv && (fabsf(s - qfv[0]) <= 8.0f || fabsf(s - qfv[1]) <= 8.0f ||
                           fabsf(s - qfv[2]) <= 8.0f || fabsf(s - qfv[3]) <= 8.0f);
        const unsigned long long m = __ballot(cand);

        if (m) { // rare: exact numpy-order hash for each flagged row
            unsigned rmask = 0;
#pragma unroll
            for (int r = 0; r < 8; ++r)
                if ((m >> (8 * r)) & 0xFFull) rmask |= 1u << r;
            while (rmask) {
                const int r = __builtin_ctz(rmask);
                rmask &= rmask - 1;
                int tr = t0 + r, br = b0;
                if (tr >= Tm1) { tr -= Tm1; br += 1; }
                // whole wave re-reads the 2KB row (cache-warm), stages padded
                const float* row = x + ((long)br * Tv + tr) * Dm + lane * 4;
                float4 w0 = *reinterpret_cast<const float4*>(row);
                float4 w1 = *reinterpret_cast<const float4*>(row + 256);
                asm volatile("s_waitcnt lgkmcnt(0)" ::: "memory");
                *reinterpret_cast<float4*>(&slab[wslab][pad0]) = w0;
                *reinterpret_cast<float4*>(&slab[wslab][pad1]) = w1;
                asm volatile("s_waitcnt lgkmcnt(0)" ::: "memory");
                int h = hash_row_lds(slab[wslab], lane & 31);
                if (lane < Bv && h == qi) atomicMax(&best[lane], tr * Bv + br);
            }
        }

        // advance to next batch of 8 rows
        t0 += 8;
        if (t0 >= Tm1) { t0 -= Tm1; b0 += 1; }
        g0 += 8;
        ++bat;
    }
}

// out[b][d] = dot(W[d,:], retrieved) + bias[d]; 256 blocks = (b, 8 d-chunks).
__global__ __launch_bounds__(256) void out_kernel(const float* __restrict__ x,
                                                  const float* __restrict__ W,
                                                  const float* __restrict__ bias,
                                                  const int* __restrict__ best,
                                                  float* __restrict__ out,
                                                  int Bv, int Tv) {
    const int b = blockIdx.x >> 3;
    const int c = blockIdx.x & 7;
    const int w = threadIdx.x >> 6, lane = threadIdx.x & 63;
    const int idx = best[b];
    float r0, r1, r2, r3, r4, r5, r6, r7;
    if (idx >= 0) {
        int t = idx / Bv, bw = idx - (idx / Bv) * Bv; // n = t*B + b
        const float* row = x + ((long)bw * Tv + t) * Dm + lane * 8;
        float4 x0 = *reinterpret_cast<const float4*>(row);
        float4 x1 = *reinterpret_cast<const float4*>(row + 4);
        r0 = x0.x; r1 = x0.y; r2 = x0.z; r3 = x0.w;
        r4 = x1.x; r5 = x1.y; r6 = x1.z; r7 = x1.w;
    } else {
        r0 = r1 = r2 = r3 = r4 = r5 = r6 = r7 = 0.f;
    }
    for (int di = w; di < 64; di += 4) {
        int d = c * 64 + di;
        const float* wrow = W + (long)d * Dm + lane * 8;
        float4 w0 = *reinterpret_cast<const float4*>(wrow);
        float4 w1 = *reinterpret_cast<const float4*>(wrow + 4);
        float acc = w0.x * r0 + w0.y * r1 + w0.z * r2 + w0.w * r3 +
                    w1.x * r4 + w1.y * r5 + w1.z * r6 + w1.w * r7;
        acc += __shfl_xor(acc, 1);
        acc += __shfl_xor(acc, 2);
        acc += __shfl_xor(acc, 4);
        acc += __shfl_xor(acc, 8);
        acc += __shfl_xor(acc, 16);
        acc += __shfl_xor(acc, 32);
        if (lane == 0) out[(long)b * Dm + d] = acc + bias[d];
    }
}

extern "C" void kernel_launch(void* const* d_in, const int* in_sizes, int n_in,
                              void* d_out, int out_size, void* d_ws, size_t ws_size,
                              hipStream_t stream) {
    const float* x = (const float*)d_in[0];
    // d_in[1] = hx_list (unused by the reference)
    const float* W = (const float*)d_in[2];
    const float* bias = (const float*)d_in[3];
    float* out = (float*)d_out;

    int Bv = in_sizes[1];                 // 32
    long xs = (long)in_sizes[0];          // B*T*D
    int Tv = (int)(xs / ((long)Bv * Dm)); // 4096

    int* best = (int*)d_ws; // [32]
    hipMemsetAsync(best, 0xFF, Bv * sizeof(int), stream); // best[b] = -1

    const int nblk = 2048;
    const long NR = (long)Bv * (Tv - 1);
    const long NBat = (NR + 7) >> 3;
    const int nwaves = nblk * 4;
    const int bpw = (int)((NBat + nwaves - 1) / nwaves);
    stream_kernel<<<nblk, 256, 0, stream>>>(x, best, Bv, Tv, bpw);

    out_kernel<<<Bv * 8, 256, 0, stream>>>(x, W, bias, best, out, Bv, Tv);
}

// Round 11
// 57.244 us; speedup vs baseline: 1.1037x; 1.0862x over previous
//
#include <hip/hip_runtime.h>

// B=32, T=4096, D=512. out[b] = retrieved[b] @ W.T + bias where retrieved[b]
// is the LAST write row (order n = t*B + b) whose int32 hash equals query b's
// hash. Hash = (int)trunc of numpy-pairwise f32 sum of row*1000 — bit-exact
// reproduction verified R1-R10.
//
// FINAL = R8 (best measured: 57.7us). Ledger:
//  R3 barrier-free fast-screen + exact-path fallback   +3.4us
//  R5 wave-per-row 1KB nt loads + fixed eps            +6.1us
//  R8 8-row batching, 16KB in flight, 3-shfl screen    +0.5us
//  R9 A/B: removing nt loads                           -5.5us (nt is load-bearing:
//     x is 256MiB == L3 size; nt avoids churning a cache that can't hold it)
//  R6 device-scope spin fusion                         -163us (L2 maintenance storm)
//  R10 per-block query-hash prologue                   -4.5us (134MB redundant reads)
// Roofline: x stream 268MB @ ~6.9TB/s fill-rate ceiling = ~39us floor;
// stream dispatch runs ~46us (~85% of ceiling); rest is init/out/gaps (~12us),
// all fusion alternatives measured null or negative.

constexpr int Dm = 512;
constexpr int LROW = 544; // padded: elem idx stored at idx + 8*(idx>>7)

typedef float nt_f4 __attribute__((ext_vector_type(4))); // builtin-compatible

// Exact numpy pairwise sum of 512 f32 (each *1000 in f32 first), by a 32-lane
// group. lane=(k<<3)|j; k=128-block, j=accumulator. Per block: r[j] sequential
// 16 terms; combine ((r0+r1)+(r2+r3))+((r4+r5)+(r6+r7)); blocks (p0+p1)+(p2+p3).
// Butterfly == numpy tree (f32 add commutative). Bit-exact (R1 verified).
__device__ __forceinline__ int hash_row_lds(const float* rowp, int lane) {
#pragma clang fp contract(off)
    int k = lane >> 3, j = lane & 7;
    const float* p = rowp + k * 136 + j;
    float r = p[0] * 1000.0f;
#pragma unroll
    for (int i = 1; i < 16; ++i) {
        float prod = p[8 * i] * 1000.0f;
        r = r + prod;
    }
    r = r + __shfl_xor(r, 1);
    r = r + __shfl_xor(r, 2);
    r = r + __shfl_xor(r, 4);
    r = r + __shfl_xor(r, 8);
    r = r + __shfl_xor(r, 16);
    return (int)r; // trunc toward zero
}

// One query row per block (single wave). Block 0 also inits best[].
__global__ __launch_bounds__(64) void init_kernel(const float* __restrict__ x,
                                                  int* __restrict__ qh_i,
                                                  float* __restrict__ qh_f,
                                                  int* __restrict__ best,
                                                  int Bv, int Tv) {
    __shared__ float slab[LROW];
    const int lane = threadIdx.x;
    const int bq = blockIdx.x;
    if (bq == 0 && lane < Bv) best[lane] = -1;
    if (bq >= Bv) return;
    const float* row = x + ((long)bq * Tv + (Tv - 1)) * Dm;
    const int idx = lane * 8;
    const int off = idx + 8 * (idx >> 7);
    *reinterpret_cast<float4*>(&slab[off]) = *reinterpret_cast<const float4*>(row + idx);
    *reinterpret_cast<float4*>(&slab[off + 4]) = *reinterpret_cast<const float4*>(row + idx + 4);
    __syncthreads();
    if (lane < 32) {
        int h = hash_row_lds(slab, lane);
        if (lane == 0) { qh_i[bq] = h; qh_f[bq] = (float)h; }
    }
}

// Batched stream: each wave owns bpw batches of 8 consecutive memory-order
// rows. Lane L owns row (L>>3), cols (L&7)*4 + c*32 (16 nt dwordx4 loads,
// 16KB in flight). Screen: per-lane sum of 64 floats + 3-step shfl in 8-lane
// groups; sound bound ~2.0, eps=8.0 (4x margin, ~0.9% flagged). Flagged rows
// re-read (cache-warm) into the verified 64-lane LDS exact hash path.
__global__ __launch_bounds__(256) void stream_kernel(const float* __restrict__ x,
                                                     const int* __restrict__ qh_i,
                                                     const float* __restrict__ qh_f,
                                                     int* __restrict__ best,
                                                     int Bv, int Tv, int bpw) {
    __shared__ float slab[4][LROW];
    const int tid = threadIdx.x;
    const int wslab = tid >> 6;
    const int lane = tid & 63;
    const int g8 = lane & 7;    // column slot within 8-lane group
    const int rloc = lane >> 3; // row within batch
    const int Tm1 = Tv - 1;
    const long NR = (long)Bv * Tm1;
    const long NBat = (NR + 7) >> 3;

    int qi = (int)0x80000000;
    if (lane < Bv) qi = qh_i[lane];
    float qfv[4];
#pragma unroll
    for (int k = 0; k < 4; ++k) {
        int q = g8 * 4 + k;
        qfv[k] = (q < Bv) ? qh_f[q] : __builtin_inff();
    }

    // LDS offsets for the exact path (padded layout, see hash_row_lds)
    const int pad0 = lane * 4 + 8 * (lane >> 5);       // elems [0,256)
    const int pad1 = 272 + lane * 4 + 8 * (lane >> 5); // elems [256,512)

    const int wave_id = blockIdx.x * 4 + wslab;
    long bat = (long)wave_id * bpw;
    const long bend = min(bat + bpw, NBat);
    if (bat >= bend) return;

    long g0 = bat * 8;
    int b0 = (int)(g0 / Tm1); // one division per wave
    int t0 = (int)(g0 - (long)b0 * Tm1);

    while (bat < bend) {
        // this lane's row within the batch (batches can cross one b-boundary)
        const bool rv = (g0 + rloc) < NR;
        int tl = t0 + rloc, bl = b0;
        if (tl >= Tm1) { tl -= Tm1; bl += 1; }
        if (!rv) { tl = 0; bl = 0; } // safe dummy address
        const float* base = x + ((long)bl * Tv + tl) * Dm + g8 * 4;

        nt_f4 v[16];
#pragma unroll
        for (int c = 0; c < 16; ++c)
            v[c] = __builtin_nontemporal_load(reinterpret_cast<const nt_f4*>(base + c * 32));

        // per-lane sum of its 64 floats (4 independent accumulators)
        float a0 = 0.f, a1 = 0.f, a2 = 0.f, a3 = 0.f;
#pragma unroll
        for (int c = 0; c < 16; c += 4) {
            a0 += (v[c].x + v[c].y) + (v[c].z + v[c].w);
            a1 += (v[c + 1].x + v[c + 1].y) + (v[c + 1].z + v[c + 1].w);
            a2 += (v[c + 2].x + v[c + 2].y) + (v[c + 2].z + v[c + 2].w);
            a3 += (v[c + 3].x + v[c + 3].y) + (v[c + 3].z + v[c + 3].w);
        }
        float s = (a0 + a1) + (a2 + a3);
        s += __shfl_xor(s, 1); // 3-step reduce within the 8-lane group
        s += __shfl_xor(s, 2);
        s += __shfl_xor(s, 4);
        s *= 1000.0f;

        bool cand = rv && (fabsf(s - qfv[0]) <= 8.0f || fabsf(s - qfv[1]) <= 8.0f ||
                           fabsf(s - qfv[2]) <= 8.0f || fabsf(s - qfv[3]) <= 8.0f);
        const unsigned long long m = __ballot(cand);

        if (m) { // rare: exact numpy-order hash for each flagged row
            unsigned rmask = 0;
#pragma unroll
            for (int r = 0; r < 8; ++r)
                if ((m >> (8 * r)) & 0xFFull) rmask |= 1u << r;
            while (rmask) {
                const int r = __builtin_ctz(rmask);
                rmask &= rmask - 1;
                int tr = t0 + r, br = b0;
                if (tr >= Tm1) { tr -= Tm1; br += 1; }
                // whole wave re-reads the 2KB row (cache-warm), stages padded
                const float* row = x + ((long)br * Tv + tr) * Dm + lane * 4;
                float4 w0 = *reinterpret_cast<const float4*>(row);
                float4 w1 = *reinterpret_cast<const float4*>(row + 256);
                asm volatile("s_waitcnt lgkmcnt(0)" ::: "memory");
                *reinterpret_cast<float4*>(&slab[wslab][pad0]) = w0;
                *reinterpret_cast<float4*>(&slab[wslab][pad1]) = w1;
                asm volatile("s_waitcnt lgkmcnt(0)" ::: "memory");
                int h = hash_row_lds(slab[wslab], lane & 31);
                if (lane < Bv && h == qi) atomicMax(&best[lane], tr * Bv + br);
            }
        }

        // advance to next batch of 8 rows
        t0 += 8;
        if (t0 >= Tm1) { t0 -= Tm1; b0 += 1; }
        g0 += 8;
        ++bat;
    }
}

// out[b][d] = dot(W[d,:], retrieved) + bias[d]; 256 blocks = (b, 8 d-chunks).
__global__ __launch_bounds__(256) void out_kernel(const float* __restrict__ x,
                                                  const float* __restrict__ W,
                                                  const float* __restrict__ bias,
                                                  const int* __restrict__ best,
                                                  float* __restrict__ out,
                                                  int Bv, int Tv) {
    const int b = blockIdx.x >> 3;
    const int c = blockIdx.x & 7;
    const int w = threadIdx.x >> 6, lane = threadIdx.x & 63;
    const int idx = best[b];
    float r0, r1, r2, r3, r4, r5, r6, r7;
    if (idx >= 0) {
        int t = idx / Bv, bw = idx - (idx / Bv) * Bv; // n = t*B + b
        const float* row = x + ((long)bw * Tv + t) * Dm + lane * 8;
        float4 x0 = *reinterpret_cast<const float4*>(row);
        float4 x1 = *reinterpret_cast<const float4*>(row + 4);
        r0 = x0.x; r1 = x0.y; r2 = x0.z; r3 = x0.w;
        r4 = x1.x; r5 = x1.y; r6 = x1.z; r7 = x1.w;
    } else {
        r0 = r1 = r2 = r3 = r4 = r5 = r6 = r7 = 0.f;
    }
    for (int di = w; di < 64; di += 4) {
        int d = c * 64 + di;
        const float* wrow = W + (long)d * Dm + lane * 8;
        float4 w0 = *reinterpret_cast<const float4*>(wrow);
        float4 w1 = *reinterpret_cast<const float4*>(wrow + 4);
        float acc = w0.x * r0 + w0.y * r1 + w0.z * r2 + w0.w * r3 +
                    w1.x * r4 + w1.y * r5 + w1.z * r6 + w1.w * r7;
        acc += __shfl_xor(acc, 1);
        acc += __shfl_xor(acc, 2);
        acc += __shfl_xor(acc, 4);
        acc += __shfl_xor(acc, 8);
        acc += __shfl_xor(acc, 16);
        acc += __shfl_xor(acc, 32);
        if (lane == 0) out[(long)b * Dm + d] = acc + bias[d];
    }
}

extern "C" void kernel_launch(void* const* d_in, const int* in_sizes, int n_in,
                              void* d_out, int out_size, void* d_ws, size_t ws_size,
                              hipStream_t stream) {
    const float* x = (const float*)d_in[0];
    // d_in[1] = hx_list (unused by the reference)
    const float* W = (const float*)d_in[2];
    const float* bias = (const float*)d_in[3];
    float* out = (float*)d_out;

    int Bv = in_sizes[1];                 // 32
    long xs = (long)in_sizes[0];          // B*T*D
    int Tv = (int)(xs / ((long)Bv * Dm)); // 4096

    int* best = (int*)d_ws;               // [64]
    int* qh_i = (int*)d_ws + 64;          // [64]
    float* qh_f = (float*)d_ws + 128;     // [64]

    init_kernel<<<Bv, 64, 0, stream>>>(x, qh_i, qh_f, best, Bv, Tv);

    const int nblk = 2048;
    const long NR = (long)Bv * (Tv - 1);
    const long NBat = (NR + 7) >> 3;
    const int nwaves = nblk * 4;
    const int bpw = (int)((NBat + nwaves - 1) / nwaves);
    stream_kernel<<<nblk, 256, 0, stream>>>(x, qh_i, qh_f, best, Bv, Tv, bpw);

    out_kernel<<<Bv * 8, 256, 0, stream>>>(x, W, bias, best, out, Bv, Tv);
}